// Round 24
// baseline (49.233 us; speedup 1.0000x reference)
//
#include <hip/hip_runtime.h>

#define NFEAT   100000
#define NBATCH  256
#define DIM     128
#define MARGIN_F 0.5f
#define FLT_BIG 3.402823466e+38f

// ---- main geometry: 625 blocks x 160 feature rows = 100000 exactly
#define NCHUNK  625
#define CROWS   160
#define NTILE   10                 // 16-row B-tiles per block
#define GRID    NCHUNK

// ---- f32 fallback geometry (R13): 1250 x 80
#define GRIDF   1250
#define RPBF    80
#define NTILEF  5

typedef __bf16 bf8_t  __attribute__((ext_vector_type(8)));
typedef short  sh8_t  __attribute__((ext_vector_type(8)));
typedef float  f32x4  __attribute__((ext_vector_type(4)));

__device__ __forceinline__ bf8_t pack8(float4 v0, float4 v1) {
  bf8_t r;
  r[0] = (__bf16)v0.x; r[1] = (__bf16)v0.y; r[2] = (__bf16)v0.z; r[3] = (__bf16)v0.w;
  r[4] = (__bf16)v1.x; r[5] = (__bf16)v1.y; r[6] = (__bf16)v1.z; r[7] = (__bf16)v1.w;
  return r;
}

template <typename VA, typename VC>
__device__ __forceinline__ auto mfma_sel(VA a, VA b, VC c, int)
    -> decltype(__builtin_amdgcn_mfma_f32_16x16x32_bf16(a, b, c, 0, 0, 0)) {
  return __builtin_amdgcn_mfma_f32_16x16x32_bf16(a, b, c, 0, 0, 0);
}
template <typename VA, typename VC>
__device__ __forceinline__ VC mfma_sel(VA a, VA b, VC c, long) {
  return __builtin_amdgcn_mfma_f32_16x16x32_bf16(
      __builtin_bit_cast(sh8_t, a), __builtin_bit_cast(sh8_t, b), c, 0, 0, 0);
}
__device__ __forceinline__ f32x4 mfma_bf16(bf8_t a, bf8_t b, f32x4 c) {
  return mfma_sel(a, b, c, 0);
}

#if defined(__has_builtin)
#if __has_builtin(__builtin_amdgcn_global_load_lds)
#define HAVE_GLLDS 1
#endif
#endif

__device__ __forceinline__ void stage16(const char* g, char* l) {
#ifdef HAVE_GLLDS
  __builtin_amdgcn_global_load_lds(
      (const __attribute__((address_space(1))) unsigned int*)g,
      (__attribute__((address_space(3))) unsigned int*)l, 16, 0, 0);
#else
  *reinterpret_cast<float4*>(l) = *reinterpret_cast<const float4*>(g);
#endif
}

// ============================================================================
// K1a: cast f32->bf16 AND re-arrange features into MFMA FRAGMENT ORDER.
//   featbX byte offset(t, ks, lane) = t*4096 + ks*1024 + lane*16,
//   holding featb[t*16 + (lane&15)][ks*32 + (lane>>4)*8 .. +8].
// R23 validated: fragment-order B (contiguous 64x16B wave-loads, 4 cache
// lines/inst instead of a 16-line gather) cut main 54 -> ~32us. Keep.
// ============================================================================
#define NG_IN   (NBATCH * DIM / 8)
#define NG_ALL  (NG_IN + NFEAT * DIM / 8)
__global__ __launch_bounds__(256) void cast_bf16(
    const float* __restrict__ inputs, const float* __restrict__ features,
    __bf16* __restrict__ inb, __bf16* __restrict__ featbX,
    float* __restrict__ out)
{
  if (blockIdx.x == 0 && threadIdx.x == 0) out[0] = 0.0f;  // K2 accumulates
  const int gid    = blockIdx.x * 256 + threadIdx.x;
  const int stride = gridDim.x * 256;
  for (int i = gid; i < NG_ALL; i += stride) {
    const float* src; __bf16* dst;
    if (i < NG_IN) {
      src = inputs + (size_t)i * 8;
      dst = inb + (size_t)i * 8;
    } else {
      const int g    = i - NG_IN;          // fragment-group id
      const int lane = g & 63;
      const int ks   = (g >> 6) & 3;
      const int t    = g >> 8;             // 0..6249
      src = features + ((size_t)(t * 16 + (lane & 15)) * DIM
                        + ks * 32 + (lane >> 4) * 8);
      dst = featbX + (size_t)g * 8;        // contiguous in g
    }
    float4 v0 = *reinterpret_cast<const float4*>(src);
    float4 v1 = *reinterpret_cast<const float4*>(src + 4);
    *reinterpret_cast<bf8_t*>(dst) = pack8(v0, v1);
  }
}

// ============================================================================
// K1b (R24): DEPTH-3 hand-asm pipeline + labels hoisted to prologue.
// R23 (+fragment-order) was the first real win (main 54 -> ~32us): the load
// SHAPE was the 22-round bottleneck. Remaining stall candidates fixed here:
//  (1) depth-2 -> DEPTH-3: vmcnt(8) keeps TWO tiles outstanding (tail 8/4/0);
//      per-tile compute (~170cyc) x 2 tiles x 4 waves/SIMD now covers L2/L3.
//  (2) the per-tile label load was a 16-LINE GATHER (stride-64B) inside the
//      asm queue -- hoisted: all 10 label gathers issue once in the prologue
//      (normal loads, drained before the asm queue starts). Steady-state
//      queue = pure 4 x 1KB contiguous loads per tile.
// All buffer/label indices compile-time after full unroll (rule #20).
// VGPR ~110 < the de-facto 128 budget (R20/R21: over => spill/sink).
// Geometry: 625 x 512 (8 waves x 2 M-tiles), zero LDS, zero barriers.
// MFMA 16x16x32 layouts (guide §3, m89/m91-verified):
//   A: lane l holds A[m0 + (l&15)][ks*32 + (l>>4)*8 + e]   (inb row-major)
//   B: lane l holds B[ks*32 + (l>>4)*8 + e][j0 + (l&15)]   (featbX frag-order)
//   D: lane l reg r = sim[m0 + (l>>4)*4 + r][j0 + (l&15)]
// ============================================================================
__global__ __launch_bounds__(512, 2) void triplet_main(
    const __bf16* __restrict__ inb, const __bf16* __restrict__ featbX,
    const int* __restrict__ targets, const int* __restrict__ flabels,
    const int* __restrict__ idx,
    float* __restrict__ ppos, float* __restrict__ pneg)
{
  const int tid   = threadIdx.x;
  const int lane  = tid & 63;
  const int wv    = tid >> 6;       // 0..7: wave owns batch rows [32wv,32wv+32)
  const int l15   = lane & 15;
  const int lg    = lane >> 4;      // 0..3
  const int chunk = blockIdx.x;     // 0..624
  const int m0    = wv * 32;
  const int frow0 = chunk * CROWS;  // first of 160 feature rows
  const int tile0 = chunk * NTILE;  // first fragment-tile index

  // ---- prologue (normal loads): A fragments, meta, ALL 10 tile labels
  bf8_t afrag[2][4];
#pragma unroll
  for (int mt = 0; mt < 2; ++mt) {
    const char* abase = (const char*)inb + (size_t)(m0 + mt * 16 + l15) * 256 + lg * 16;
#pragma unroll
    for (int ks = 0; ks < 4; ++ks)
      afrag[mt][ks] = *reinterpret_cast<const bf8_t*>(abase + ks * 64);
  }
  int meta[2][4];
#pragma unroll
  for (int mt = 0; mt < 2; ++mt)
#pragma unroll
    for (int rr = 0; rr < 4; ++rr) {
      const int row = m0 + mt * 16 + lg * 4 + rr;
      meta[mt][rr] = (idx[row] << 10) | targets[row];   // lab<1000: 10 bits
    }
  int lab[NTILE];
#pragma unroll
  for (int t = 0; t < NTILE; ++t)
    lab[t] = flabels[frow0 + t * 16 + l15];             // 10 gathers, once

  float minpos[2][4], maxneg[2][4];
#pragma unroll
  for (int mt = 0; mt < 2; ++mt)
#pragma unroll
    for (int rr = 0; rr < 4; ++rr) { minpos[mt][rr] = FLT_BIG; maxneg[mt][rr] = -FLT_BIG; }

  // ---- hand pipeline: SGPR base + 32-bit voffsets (frag-order: contiguous)
  const unsigned long long fb = (unsigned long long)featbX;
  const unsigned vlane = (unsigned)lane * 16u;          // lane slot in tile

#define SCHEDB()  __builtin_amdgcn_sched_barrier(0)
#define WAITVM(N) asm volatile("s_waitcnt vmcnt(" #N ")" ::: "memory")

  // tile t: 4 x 1KB contiguous B-frag loads, volatile asm (un-sinkable)
#define LOADT_ASM(buf, t)                                                     \
  do {                                                                        \
    unsigned vo_ = vlane + (unsigned)(tile0 + (t)) * 4096u;                   \
    asm volatile("global_load_dwordx4 %0, %1, %2 offset:0"                    \
                 : "=v"(buf[0]) : "v"(vo_), "s"(fb));                         \
    asm volatile("global_load_dwordx4 %0, %1, %2 offset:1024"                 \
                 : "=v"(buf[1]) : "v"(vo_), "s"(fb));                         \
    asm volatile("global_load_dwordx4 %0, %1, %2 offset:2048"                 \
                 : "=v"(buf[2]) : "v"(vo_), "s"(fb));                         \
    asm volatile("global_load_dwordx4 %0, %1, %2 offset:3072"                 \
                 : "=v"(buf[3]) : "v"(vo_), "s"(fb));                         \
  } while (0)

#define TILE_COMPUTE(buf, labj, t)                                 \
  do {                                                             \
    f32x4 acc0 = {0.f, 0.f, 0.f, 0.f};                             \
    f32x4 acc1 = {0.f, 0.f, 0.f, 0.f};                             \
    _Pragma("unroll")                                              \
    for (int ks = 0; ks < 4; ++ks) {                               \
      acc0 = mfma_bf16(afrag[0][ks], buf[ks], acc0);               \
      acc1 = mfma_bf16(afrag[1][ks], buf[ks], acc1);               \
    }                                                              \
    const int j_ = frow0 + (t) * 16 + l15;                         \
    _Pragma("unroll")                                              \
    for (int rr = 0; rr < 4; ++rr) {                               \
      {                                                            \
        const int  m_   = meta[0][rr];                             \
        const bool same = ((labj) == (m_ & 1023));                 \
        const bool self = (j_ == (m_ >> 10));                      \
        minpos[0][rr] = fminf(minpos[0][rr],                       \
                              (same && !self) ? acc0[rr] : FLT_BIG); \
        maxneg[0][rr] = fmaxf(maxneg[0][rr],                       \
                              same ? -FLT_BIG : acc0[rr]);         \
      }                                                            \
      {                                                            \
        const int  m_   = meta[1][rr];                             \
        const bool same = ((labj) == (m_ & 1023));                 \
        const bool self = (j_ == (m_ >> 10));                      \
        minpos[1][rr] = fminf(minpos[1][rr],                       \
                              (same && !self) ? acc1[rr] : FLT_BIG); \
        maxneg[1][rr] = fmaxf(maxneg[1][rr],                       \
                              same ? -FLT_BIG : acc1[rr]);         \
      }                                                            \
    }                                                              \
  } while (0)

  // drain ALL prologue loads (A, meta, labels) so the vmcnt queue holds only
  // our asm loads; sched_barriers pin the boundary.
  SCHEDB(); WAITVM(0); SCHEDB();

  // depth-3: three named buffers, two tiles outstanding in steady state
  bf8_t b0[4], b1[4], b2[4];
  LOADT_ASM(b0, 0);
  LOADT_ASM(b1, 1);
  LOADT_ASM(b2, 2);

#pragma unroll
  for (int t = 0; t < NTILE; ++t) {
    // wait for tile t's 4 loads: outstanding after wait = min queue depth
    if (t <= NTILE - 3)      { WAITVM(8); }   // 2 tiles still in flight
    else if (t == NTILE - 2) { WAITVM(4); }
    else                     { WAITVM(0); }
    SCHEDB();
    if ((t % 3) == 0)      { TILE_COMPUTE(b0, lab[t], t); if (t + 3 < NTILE) LOADT_ASM(b0, t + 3); }
    else if ((t % 3) == 1) { TILE_COMPUTE(b1, lab[t], t); if (t + 3 < NTILE) LOADT_ASM(b1, t + 3); }
    else                   { TILE_COMPUTE(b2, lab[t], t); if (t + 3 < NTILE) LOADT_ASM(b2, t + 3); }
  }
#undef LOADT_ASM
#undef TILE_COMPUTE
#undef WAITVM
#undef SCHEDB

  // ---- reduce across the 16-lane col group; contiguous [chunk][row] write
#pragma unroll
  for (int mt = 0; mt < 2; ++mt)
#pragma unroll
    for (int rr = 0; rr < 4; ++rr) {
      float mp = minpos[mt][rr], mn = maxneg[mt][rr];
#pragma unroll
      for (int m = 1; m < 16; m <<= 1) {
        mp = fminf(mp, __shfl_xor(mp, m, 64));
        mn = fmaxf(mn, __shfl_xor(mn, m, 64));
      }
      if (l15 == 0) {
        const int row = m0 + mt * 16 + lg * 4 + rr;
        ppos[chunk * NBATCH + row] = mp;
        pneg[chunk * NBATCH + row] = mn;
      }
    }
}

// ============================================================================
// Fallback (ws too small): R13 f32 monolith, known-good ~43us path.
// ============================================================================
__global__ __launch_bounds__(512, 2) void triplet_partial_f32(
    const float* __restrict__ inputs, const float* __restrict__ features,
    const int* __restrict__ targets, const int* __restrict__ flabels,
    const int* __restrict__ idx,
    float* __restrict__ ppos, float* __restrict__ pneg,
    float* __restrict__ out)
{
  __shared__ char sB[RPBF * DIM * 4];

  const int tid  = threadIdx.x;
  const int lane = tid & 63;
  const int wv   = tid >> 6;
  const int l15  = lane & 15;
  const int lg   = lane >> 4;
  const int m0   = wv * 32;
  const int blk  = blockIdx.x;
  const int rowbase = blk * RPBF;

  if (blk == 0 && tid == 0) out[0] = 0.0f;

#pragma unroll
  for (int i = 0; i < NTILEF; ++i) {
    const int p    = i * 8192 + tid * 16;
    const int prow = p >> 9;
    const int scol = (p & 511) ^ ((prow & 7) << 4);
    stage16((const char*)features + (size_t)(rowbase + prow) * 512 + scol, &sB[p]);
  }

  bf8_t afrag[2][4];
#pragma unroll
  for (int mt = 0; mt < 2; ++mt) {
    const float* ap = inputs + (m0 + mt * 16 + l15) * DIM;
    float4 v0[4], v1[4];
#pragma unroll
    for (int ks = 0; ks < 4; ++ks) {
      const int k = ks * 32 + lg * 8;
      v0[ks] = *reinterpret_cast<const float4*>(ap + k);
      v1[ks] = *reinterpret_cast<const float4*>(ap + k + 4);
    }
#pragma unroll
    for (int ks = 0; ks < 4; ++ks)
      afrag[mt][ks] = pack8(v0[ks], v1[ks]);
  }

  int lab[NTILEF];
#pragma unroll
  for (int t = 0; t < NTILEF; ++t)
    lab[t] = flabels[rowbase + t * 16 + l15];

  int meta[2][4];
#pragma unroll
  for (int mt = 0; mt < 2; ++mt)
#pragma unroll
    for (int rr = 0; rr < 4; ++rr) {
      const int row = m0 + mt * 16 + lg * 4 + rr;
      meta[mt][rr] = (idx[row] << 10) | targets[row];
    }

  float minpos[2][4], maxneg[2][4];
#pragma unroll
  for (int mt = 0; mt < 2; ++mt)
#pragma unroll
    for (int rr = 0; rr < 4; ++rr) { minpos[mt][rr] = FLT_BIG; maxneg[mt][rr] = -FLT_BIG; }

  __syncthreads();

  const int swz = (l15 & 7) << 4;
#pragma unroll
  for (int t = 0; t < NTILEF; ++t) {
    const char* rbase = &sB[(t * 16 + l15) * 512];
    const int   j     = rowbase + t * 16 + l15;
    const int   labj  = lab[t];

    f32x4 acc0 = {0.f, 0.f, 0.f, 0.f};
    f32x4 acc1 = {0.f, 0.f, 0.f, 0.f};
#pragma unroll
    for (int ks = 0; ks < 4; ++ks) {
      const int o = ks * 128 + lg * 32;
      float4 v0 = *reinterpret_cast<const float4*>(rbase + ((o)      ^ swz));
      float4 v1 = *reinterpret_cast<const float4*>(rbase + ((o + 16) ^ swz));
      bf8_t bf = pack8(v0, v1);
      acc0 = mfma_bf16(afrag[0][ks], bf, acc0);
      acc1 = mfma_bf16(afrag[1][ks], bf, acc1);
    }
#pragma unroll
    for (int rr = 0; rr < 4; ++rr) {
      {
        const int  m = meta[0][rr];
        const bool same = (labj == (m & 1023));
        const bool self = (j == (m >> 10));
        minpos[0][rr] = fminf(minpos[0][rr], (same && !self) ? acc0[rr] : FLT_BIG);
        maxneg[0][rr] = fmaxf(maxneg[0][rr], same ? -FLT_BIG : acc0[rr]);
      }
      {
        const int  m = meta[1][rr];
        const bool same = (labj == (m & 1023));
        const bool self = (j == (m >> 10));
        minpos[1][rr] = fminf(minpos[1][rr], (same && !self) ? acc1[rr] : FLT_BIG);
        maxneg[1][rr] = fmaxf(maxneg[1][rr], same ? -FLT_BIG : acc1[rr]);
      }
    }
  }

#pragma unroll
  for (int mt = 0; mt < 2; ++mt)
#pragma unroll
    for (int rr = 0; rr < 4; ++rr) {
      float mp = minpos[mt][rr], mn = maxneg[mt][rr];
#pragma unroll
      for (int m = 1; m < 16; m <<= 1) {
        mp = fminf(mp, __shfl_xor(mp, m, 64));
        mn = fmaxf(mn, __shfl_xor(mn, m, 64));
      }
      if (l15 == 0) {
        const int row = m0 + mt * 16 + lg * 4 + rr;
        ppos[blk * NBATCH + row] = mp;
        pneg[blk * NBATCH + row] = mn;
      }
    }
}

// Kernel 2: one block per batch row; fold nblk partials, hinge, atomic mean.
__global__ __launch_bounds__(256) void triplet_reduce(
    const float* __restrict__ ppos, const float* __restrict__ pneg,
    float* __restrict__ out, int nblk)
{
  const int r = blockIdx.x;
  const int t = threadIdx.x;
  float mp = FLT_BIG, mn = -FLT_BIG;
  for (int b = t; b < nblk; b += 256) {
    mp = fminf(mp, ppos[b * NBATCH + r]);
    mn = fmaxf(mn, pneg[b * NBATCH + r]);
  }
#pragma unroll
  for (int m = 1; m < 64; m <<= 1) {
    mp = fminf(mp, __shfl_xor(mp, m, 64));
    mn = fmaxf(mn, __shfl_xor(mn, m, 64));
  }
  __shared__ float smp[4], smn[4];
  if ((t & 63) == 0) { smp[t >> 6] = mp; smn[t >> 6] = mn; }
  __syncthreads();
  if (t == 0) {
    mp = fminf(fminf(smp[0], smp[1]), fminf(smp[2], smp[3]));
    mn = fmaxf(fmaxf(smn[0], smn[1]), fmaxf(smn[2], smn[3]));
    float loss = mn - mp + MARGIN_F;
    loss = loss > 0.f ? loss : 0.f;
    atomicAdd(out, loss * (1.0f / NBATCH));
  }
}

extern "C" void kernel_launch(void* const* d_in, const int* in_sizes, int n_in,
                              void* d_out, int out_size, void* d_ws, size_t ws_size,
                              hipStream_t stream) {
  const float* inputs   = (const float*)d_in[0];
  const float* features = (const float*)d_in[1];
  const int*   targets  = (const int*)d_in[2];
  const int*   flabels  = (const int*)d_in[3];
  const int*   idx      = (const int*)d_in[4];
  float* out = (float*)d_out;

  const size_t featb_bytes = (size_t)NFEAT * DIM * 2;      // 25.6 MB
  const size_t inb_bytes   = (size_t)NBATCH * DIM * 2;     // 64 KB
  const size_t part_bytes  = (size_t)NCHUNK * NBATCH * 4;  // 640 KB each

  if (ws_size >= featb_bytes + inb_bytes + 2 * part_bytes) {
    __bf16* featbX = (__bf16*)d_ws;
    __bf16* inb    = (__bf16*)((char*)d_ws + featb_bytes);
    float*  ppos   = (float*)((char*)d_ws + featb_bytes + inb_bytes);
    float*  pneg   = ppos + (size_t)NCHUNK * NBATCH;
    cast_bf16<<<2048, 256, 0, stream>>>(inputs, features, inb, featbX, out);
    triplet_main<<<GRID, 512, 0, stream>>>(inb, featbX, targets, flabels, idx, ppos, pneg);
    triplet_reduce<<<NBATCH, 256, 0, stream>>>(ppos, pneg, out, NCHUNK);
  } else {
    float* ppos = (float*)d_ws;                       // [GRIDF][256]
    float* pneg = ppos + (size_t)GRIDF * NBATCH;      // ~2.56 MB total
    triplet_partial_f32<<<GRIDF, 512, 0, stream>>>(inputs, features, targets,
                                                   flabels, idx, ppos, pneg, out);
    triplet_reduce<<<NBATCH, 256, 0, stream>>>(ppos, pneg, out, GRIDF);
  }
}